// Round 2
// baseline (717.661 us; speedup 1.0000x reference)
//
#include <hip/hip_runtime.h>

// ---------- types ----------
typedef __attribute__((ext_vector_type(8))) short bf16x8;   // 8 bf16 = 4 VGPR
typedef __attribute__((ext_vector_type(4))) float f32x4;    // MFMA C/D frag

__device__ __forceinline__ float b2f(short s) {
  union { unsigned u; float f; } c;
  c.u = ((unsigned)(unsigned short)s) << 16;
  return c.f;
}
__device__ __forceinline__ short f2b(float f) {
  union { unsigned u; float f; } c;
  c.f = f;
  unsigned r = (c.u + 0x7FFFu + ((c.u >> 16) & 1u)) >> 16;  // RNE
  return (short)r;
}

// async global->LDS, 16B per lane (guide §5: width=16, the 874 TF variant)
__device__ __forceinline__ void async16(const void* g, void* l) {
  __builtin_amdgcn_global_load_lds(
      (const __attribute__((address_space(1))) unsigned*)g,
      (__attribute__((address_space(3))) unsigned*)l, 16, 0, 0);
}

// ---------------------------------------------------------------------------
// fp32 -> bf16 conversion pre-pass (inputs are float32 per the reference).
// ---------------------------------------------------------------------------
__global__ __launch_bounds__(256)
void f32_to_bf16(const float* __restrict__ src, short* __restrict__ dst, int n) {
  int i = (blockIdx.x * blockDim.x + threadIdx.x) * 4;
  if (i < n) {
    float4 v = *(const float4*)(src + i);
    short4 o;
    o.x = f2b(v.x); o.y = f2b(v.y); o.z = f2b(v.z); o.w = f2b(v.w);
    *(short4*)(dst + i) = o;
  }
}

// ---------------------------------------------------------------------------
// GEMM: C[M,N] = A[M,K] @ Bw[N,K]^T + bias[N]   (torch Linear layout)
// A,Bw bf16; bias fp32; output bf16 (F32OUT=false) or fp32 (F32OUT=true).
// 128x128 tile, BK=32, 256 thr = 4 waves, wave = 64x64 via 4x4 of 16x16x32.
// ---------------------------------------------------------------------------
template <bool F32OUT>
__global__ __launch_bounds__(256)
void gemm_bt_bias(const short* __restrict__ A, const short* __restrict__ Bw,
                  const float* __restrict__ bias, void* __restrict__ Cv,
                  int M, int N, int K) {
  __shared__ short lsA[128 * 32];
  __shared__ short lsB[128 * 32];
  const int tid  = threadIdx.x;
  const int wave = tid >> 6, lane = tid & 63;
  const int quad = lane >> 4, lrow = lane & 15;
  const int m0 = blockIdx.y * 128, n0 = blockIdx.x * 128;
  const int wm = (wave >> 1) * 64, wn = (wave & 1) * 64;

  f32x4 zero = {0.f, 0.f, 0.f, 0.f};
  f32x4 acc[4][4];
#pragma unroll
  for (int i = 0; i < 4; i++)
#pragma unroll
    for (int j = 0; j < 4; j++) acc[i][j] = zero;

  // staging map: 512 chunks of 8 bf16 per tile; thread t does chunks t, t+256
  const int r0 = tid >> 2, c0 = (tid & 3) * 8;
  const short* Ab  = A  + (size_t)(m0 + r0) * K + c0;
  const short* Ab2 = A  + (size_t)(m0 + r0 + 64) * K + c0;
  const short* Bb  = Bw + (size_t)(n0 + r0) * K + c0;
  const short* Bb2 = Bw + (size_t)(n0 + r0 + 64) * K + c0;

  for (int k0 = 0; k0 < K; k0 += 32) {
    async16(Ab  + k0, lsA + tid * 8);
    async16(Ab2 + k0, lsA + (tid + 256) * 8);
    async16(Bb  + k0, lsB + tid * 8);
    async16(Bb2 + k0, lsB + (tid + 256) * 8);
    __syncthreads();   // drains vmcnt (global_load_lds) + barrier

    bf16x8 af[4], bfr[4];
#pragma unroll
    for (int i = 0; i < 4; i++)
      af[i] = *(const bf16x8*)(lsA + (wm + i * 16 + lrow) * 32 + quad * 8);
#pragma unroll
    for (int j = 0; j < 4; j++)
      bfr[j] = *(const bf16x8*)(lsB + (wn + j * 16 + lrow) * 32 + quad * 8);
#pragma unroll
    for (int i = 0; i < 4; i++)
#pragma unroll
      for (int j = 0; j < 4; j++)
        acc[i][j] = __builtin_amdgcn_mfma_f32_16x16x32_bf16(af[i], bfr[j], acc[i][j], 0, 0, 0);
    __syncthreads();   // protect LDS before next staging
  }

  // epilogue: C/D layout col=lane&15, row=quad*4+reg (guide §3, m89-verified)
#pragma unroll
  for (int j = 0; j < 4; j++) {
    const int col = n0 + wn + j * 16 + lrow;
    const float bv = bias[col];
#pragma unroll
    for (int i = 0; i < 4; i++) {
      const int rowb = m0 + wm + i * 16 + quad * 4;
#pragma unroll
      for (int r = 0; r < 4; r++) {
        const float val = acc[i][j][r] + bv;
        if (F32OUT)
          ((float*)Cv)[(size_t)(rowb + r) * N + col] = val;
        else
          ((short*)Cv)[(size_t)(rowb + r) * N + col] = f2b(val);
      }
    }
  }
}

// ---------------------------------------------------------------------------
// Flash GQA attention. Q:[4096,2048] bf16, K/V:[4096,512] bf16, O:[4096,2048].
// grid: x = q-tile (S/64), y = b*32 + h. Block 256 thr = 4 waves;
// wave w owns q-rows [w*16, w*16+16) of the 64-row Q tile.
// ---------------------------------------------------------------------------
#define S_LEN 2048
#define HID   2048
#define KVD   512

__global__ __launch_bounds__(256)
void gqa_flash(const short* __restrict__ Q, const short* __restrict__ Kb,
               const short* __restrict__ Vb, short* __restrict__ O) {
  __shared__ short lsQ[64 * 64];
  __shared__ short lsK[64 * 64];
  __shared__ short lsVt[64 * 64];        // V transposed: [d][key]
  __shared__ short lsP[4][16 * 64];      // per-wave P strip (C->A layout xform)

  const int tid  = threadIdx.x;
  const int wave = tid >> 6, lane = tid & 63;
  const int quad = lane >> 4, lrow = lane & 15;
  const int bh = blockIdx.y, b = bh >> 5, h = bh & 31, kvh = h >> 2;
  const int q0 = blockIdx.x * 64;

  // staging map: 64x64 tile = 512 chunks of 8; thread t does chunks t, t+256
  const int r0 = tid >> 3, c0 = (tid & 7) * 8;

  async16(Q + (size_t)(b * S_LEN + q0 + r0) * HID + h * 64 + c0, lsQ + tid * 8);
  async16(Q + (size_t)(b * S_LEN + q0 + r0 + 32) * HID + h * 64 + c0, lsQ + (tid + 256) * 8);

  float m_r[4], l_r[4];
  f32x4 zero = {0.f, 0.f, 0.f, 0.f};
  f32x4 o[4];
#pragma unroll
  for (int r = 0; r < 4; r++) { m_r[r] = -1e30f; l_r[r] = 0.f; }
#pragma unroll
  for (int j = 0; j < 4; j++) o[j] = zero;

  const short* Kbase = Kb + (size_t)b * S_LEN * KVD + kvh * 64;
  const short* Vbase = Vb + (size_t)b * S_LEN * KVD + kvh * 64;
  const float scale = 0.125f;  // 1/sqrt(64)

  for (int k0 = 0; k0 < S_LEN; k0 += 64) {
    // stage K tile [64 keys][64 d]
    async16(Kbase + (size_t)(k0 + r0) * KVD + c0, lsK + tid * 8);
    async16(Kbase + (size_t)(k0 + r0 + 32) * KVD + c0, lsK + (tid + 256) * 8);
    // stage V transposed (manual: global_load_lds can't scatter)
    for (int c = tid; c < 512; c += 256) {
      const int key = c >> 3, dc = (c & 7) * 8;
      bf16x8 vv = *(const bf16x8*)(Vbase + (size_t)(k0 + key) * KVD + dc);
#pragma unroll
      for (int jj = 0; jj < 8; jj++) lsVt[(dc + jj) * 64 + key] = vv[jj];
    }
    __syncthreads();

    // S = Q K^T for this wave's 16 q-rows x 64 keys
    bf16x8 aq0 = *(const bf16x8*)(lsQ + (wave * 16 + lrow) * 64 + quad * 8);
    bf16x8 aq1 = *(const bf16x8*)(lsQ + (wave * 16 + lrow) * 64 + 32 + quad * 8);
    f32x4 s[4];
#pragma unroll
    for (int j = 0; j < 4; j++) {
      bf16x8 bk0 = *(const bf16x8*)(lsK + (j * 16 + lrow) * 64 + quad * 8);
      bf16x8 bk1 = *(const bf16x8*)(lsK + (j * 16 + lrow) * 64 + 32 + quad * 8);
      f32x4 t = zero;
      t = __builtin_amdgcn_mfma_f32_16x16x32_bf16(aq0, bk0, t, 0, 0, 0);
      t = __builtin_amdgcn_mfma_f32_16x16x32_bf16(aq1, bk1, t, 0, 0, 0);
      s[j] = t;
    }

    // online softmax; lane holds rows quad*4+r, col j*16+lrow
    float mnew[4], rowsum[4];
#pragma unroll
    for (int r = 0; r < 4; r++) {
      float mx = fmaxf(fmaxf(s[0][r], s[1][r]), fmaxf(s[2][r], s[3][r]));
#pragma unroll
      for (int off = 1; off < 16; off <<= 1) mx = fmaxf(mx, __shfl_xor(mx, off));
      mnew[r] = fmaxf(m_r[r], mx * scale);
      rowsum[r] = 0.f;
    }
#pragma unroll
    for (int j = 0; j < 4; j++)
#pragma unroll
      for (int r = 0; r < 4; r++) {
        float p = __expf(s[j][r] * scale - mnew[r]);
        rowsum[r] += p;
        lsP[wave][(quad * 4 + r) * 64 + j * 16 + lrow] = f2b(p);
      }
#pragma unroll
    for (int r = 0; r < 4; r++) {
#pragma unroll
      for (int off = 1; off < 16; off <<= 1) rowsum[r] += __shfl_xor(rowsum[r], off);
      const float alpha = __expf(m_r[r] - mnew[r]);
      l_r[r] = l_r[r] * alpha + rowsum[r];
      m_r[r] = mnew[r];
#pragma unroll
      for (int j = 0; j < 4; j++) o[j][r] *= alpha;
    }

    // O += P V  (P from per-wave LDS strip in A-layout; Vt gives contiguous B-frags)
    bf16x8 ap0 = *(const bf16x8*)(lsP[wave] + lrow * 64 + quad * 8);
    bf16x8 ap1 = *(const bf16x8*)(lsP[wave] + lrow * 64 + 32 + quad * 8);
#pragma unroll
    for (int j = 0; j < 4; j++) {
      bf16x8 bv0 = *(const bf16x8*)(lsVt + (j * 16 + lrow) * 64 + quad * 8);
      bf16x8 bv1 = *(const bf16x8*)(lsVt + (j * 16 + lrow) * 64 + 32 + quad * 8);
      o[j] = __builtin_amdgcn_mfma_f32_16x16x32_bf16(ap0, bv0, o[j], 0, 0, 0);
      o[j] = __builtin_amdgcn_mfma_f32_16x16x32_bf16(ap1, bv1, o[j], 0, 0, 0);
    }
    __syncthreads();
  }

  // epilogue: normalize and store
#pragma unroll
  for (int j = 0; j < 4; j++)
#pragma unroll
    for (int r = 0; r < 4; r++) {
      const int row = q0 + wave * 16 + quad * 4 + r;
      const int col = h * 64 + j * 16 + lrow;
      O[(size_t)(b * S_LEN + row) * HID + col] = f2b(o[j][r] / l_r[r]);
    }
}

// ---------------------------------------------------------------------------
extern "C" void kernel_launch(void* const* d_in, const int* in_sizes, int n_in,
                              void* d_out, int out_size, void* d_ws, size_t ws_size,
                              hipStream_t stream) {
  const float* x  = (const float*)d_in[0];
  const float* wq = (const float*)d_in[1];
  const float* bq = (const float*)d_in[2];
  const float* wk = (const float*)d_in[3];
  const float* bk = (const float*)d_in[4];
  const float* wv = (const float*)d_in[5];
  const float* bv = (const float*)d_in[6];
  const float* wo = (const float*)d_in[7];
  const float* bo = (const float*)d_in[8];
  float* out = (float*)d_out;

  // workspace layout (bf16 shorts):
  //  xb 8.4M | wqb 4.2M | wkb 1.05M | wvb 1.05M | wob 4.2M |
  //  Qb 8.4M | Kb 2.1M | Vb 2.1M | AO 8.4M   => ~76 MB total
  short* xb  = (short*)d_ws;
  short* wqb = xb  + (size_t)4096 * 2048;
  short* wkb = wqb + (size_t)2048 * 2048;
  short* wvb = wkb + (size_t)512 * 2048;
  short* wob = wvb + (size_t)512 * 2048;
  short* Qb  = wob + (size_t)2048 * 2048;
  short* Kb  = Qb  + (size_t)4096 * 2048;
  short* Vb  = Kb  + (size_t)4096 * 512;
  short* AO  = Vb  + (size_t)4096 * 512;

  dim3 blk(256);
  // conversion pre-pass (all counts divisible by 1024)
  f32_to_bf16<<<4096 * 2048 / 1024, blk, 0, stream>>>(x,  xb,  4096 * 2048);
  f32_to_bf16<<<2048 * 2048 / 1024, blk, 0, stream>>>(wq, wqb, 2048 * 2048);
  f32_to_bf16<<< 512 * 2048 / 1024, blk, 0, stream>>>(wk, wkb, 512 * 2048);
  f32_to_bf16<<< 512 * 2048 / 1024, blk, 0, stream>>>(wv, wvb, 512 * 2048);
  f32_to_bf16<<<2048 * 2048 / 1024, blk, 0, stream>>>(wo, wob, 2048 * 2048);

  gemm_bt_bias<false><<<dim3(2048 / 128, 4096 / 128), blk, 0, stream>>>(xb, wqb, bq, Qb, 4096, 2048, 2048);
  gemm_bt_bias<false><<<dim3(512 / 128, 4096 / 128), blk, 0, stream>>>(xb, wkb, bk, Kb, 4096, 512, 2048);
  gemm_bt_bias<false><<<dim3(512 / 128, 4096 / 128), blk, 0, stream>>>(xb, wvb, bv, Vb, 4096, 512, 2048);
  gqa_flash<<<dim3(2048 / 64, 64), blk, 0, stream>>>(Qb, Kb, Vb, AO);
  gemm_bt_bias<true><<<dim3(2048 / 128, 4096 / 128), blk, 0, stream>>>(AO, wob, bo, out, 4096, 2048, 2048);
}

// Round 3
// 550.569 us; speedup vs baseline: 1.3035x; 1.3035x over previous
//
#include <hip/hip_runtime.h>

// ---------- types ----------
typedef __attribute__((ext_vector_type(8))) short bf16x8;   // 8 bf16 = 4 VGPR
typedef __attribute__((ext_vector_type(4))) float f32x4;    // MFMA C/D frag

__device__ __forceinline__ float b2f(short s) {
  union { unsigned u; float f; } c;
  c.u = ((unsigned)(unsigned short)s) << 16;
  return c.f;
}
__device__ __forceinline__ short f2b(float f) {
  union { unsigned u; float f; } c;
  c.f = f;
  unsigned r = (c.u + 0x7FFFu + ((c.u >> 16) & 1u)) >> 16;  // RNE
  return (short)r;
}

// async global->LDS, 16B per lane (guide §5: width=16, the 874 TF variant)
__device__ __forceinline__ void async16(const void* g, void* l) {
  __builtin_amdgcn_global_load_lds(
      (const __attribute__((address_space(1))) unsigned*)g,
      (__attribute__((address_space(3))) unsigned*)l, 16, 0, 0);
}

// ---------------------------------------------------------------------------
// fp32 -> bf16 conversion pre-pass (inputs are float32 per the reference).
// ---------------------------------------------------------------------------
__global__ __launch_bounds__(256)
void f32_to_bf16(const float* __restrict__ src, short* __restrict__ dst, int n) {
  int i = (blockIdx.x * blockDim.x + threadIdx.x) * 4;
  if (i < n) {
    float4 v = *(const float4*)(src + i);
    short4 o;
    o.x = f2b(v.x); o.y = f2b(v.y); o.z = f2b(v.z); o.w = f2b(v.w);
    *(short4*)(dst + i) = o;
  }
}

// ---------------------------------------------------------------------------
// GEMM: C[M,N] = A[M,K] @ Bw[N,K]^T + bias[N]   (torch Linear layout)
// A,Bw bf16; bias fp32; output bf16 (F32OUT=false) or fp32 (F32OUT=true).
// 128x128 tile, BK=32, 256 thr = 4 waves, wave = 64x64 via 4x4 of 16x16x32.
// ---------------------------------------------------------------------------
template <bool F32OUT>
__global__ __launch_bounds__(256)
void gemm_bt_bias(const short* __restrict__ A, const short* __restrict__ Bw,
                  const float* __restrict__ bias, void* __restrict__ Cv,
                  int M, int N, int K) {
  __shared__ short lsA[128 * 32];
  __shared__ short lsB[128 * 32];
  const int tid  = threadIdx.x;
  const int wave = tid >> 6, lane = tid & 63;
  const int quad = lane >> 4, lrow = lane & 15;
  const int m0 = blockIdx.y * 128, n0 = blockIdx.x * 128;
  const int wm = (wave >> 1) * 64, wn = (wave & 1) * 64;

  f32x4 zero = {0.f, 0.f, 0.f, 0.f};
  f32x4 acc[4][4];
#pragma unroll
  for (int i = 0; i < 4; i++)
#pragma unroll
    for (int j = 0; j < 4; j++) acc[i][j] = zero;

  const int r0 = tid >> 2, c0 = (tid & 3) * 8;
  const short* Ab  = A  + (size_t)(m0 + r0) * K + c0;
  const short* Ab2 = A  + (size_t)(m0 + r0 + 64) * K + c0;
  const short* Bb  = Bw + (size_t)(n0 + r0) * K + c0;
  const short* Bb2 = Bw + (size_t)(n0 + r0 + 64) * K + c0;

  for (int k0 = 0; k0 < K; k0 += 32) {
    async16(Ab  + k0, lsA + tid * 8);
    async16(Ab2 + k0, lsA + (tid + 256) * 8);
    async16(Bb  + k0, lsB + tid * 8);
    async16(Bb2 + k0, lsB + (tid + 256) * 8);
    __syncthreads();

    bf16x8 af[4], bfr[4];
#pragma unroll
    for (int i = 0; i < 4; i++)
      af[i] = *(const bf16x8*)(lsA + (wm + i * 16 + lrow) * 32 + quad * 8);
#pragma unroll
    for (int j = 0; j < 4; j++)
      bfr[j] = *(const bf16x8*)(lsB + (wn + j * 16 + lrow) * 32 + quad * 8);
#pragma unroll
    for (int i = 0; i < 4; i++)
#pragma unroll
      for (int j = 0; j < 4; j++)
        acc[i][j] = __builtin_amdgcn_mfma_f32_16x16x32_bf16(af[i], bfr[j], acc[i][j], 0, 0, 0);
    __syncthreads();
  }

#pragma unroll
  for (int j = 0; j < 4; j++) {
    const int col = n0 + wn + j * 16 + lrow;
    const float bv = bias[col];
#pragma unroll
    for (int i = 0; i < 4; i++) {
      const int rowb = m0 + wm + i * 16 + quad * 4;
#pragma unroll
      for (int r = 0; r < 4; r++) {
        const float val = acc[i][j][r] + bv;
        if (F32OUT)
          ((float*)Cv)[(size_t)(rowb + r) * N + col] = val;
        else
          ((short*)Cv)[(size_t)(rowb + r) * N + col] = f2b(val);
      }
    }
  }
}

// ---------------------------------------------------------------------------
// Flash GQA v2. Block = one kv-head x 4 q-heads x 32 q-rows/head.
// Wave w handles head kvh*4+w. K/V staged ONCE per block-iter (4x amortized).
// All LDS rows stride 72 shorts (144B: 16B-aligned, conflict-free for both
// b128 frag reads (bank=4(lrow+quad)+dw) and staging writes).
// grid: x = S/32 q-tiles (64), y = b*8 + kvh (16).
// ---------------------------------------------------------------------------
#define S_LEN 2048
#define HID   2048
#define KVD   512
#define ST    72          // LDS row stride (shorts)

__global__ __launch_bounds__(256)
void gqa_flash(const short* __restrict__ Q, const short* __restrict__ Kb,
               const short* __restrict__ Vb, short* __restrict__ O) {
  // lsQP: Q strips [4 heads][32 q][ST] during preamble; reused as per-wave
  // P strips [wave][32 q][ST] in the k-loop (Q frags hoisted to regs first).
  __shared__ __align__(16) short lsQP[4 * 32 * ST];
  __shared__ __align__(16) short lsK[64 * ST];
  __shared__ __align__(16) short lsVt[64 * ST];   // V^T: [d][key]

  const int tid  = threadIdx.x;
  const int wave = tid >> 6, lane = tid & 63;
  const int quad = lane >> 4, lrow = lane & 15;
  const int by = blockIdx.y, b = by >> 3, kvh = by & 7;
  const int h = kvh * 4 + wave;
  const int q0 = blockIdx.x * 32;

  // ---- stage Q once, scaled by 1/8 (exact in bf16) ----
  for (int c = tid; c < 1024; c += 256) {
    const int head = c >> 8, qr = (c >> 3) & 31, ch = (c & 7) * 8;
    bf16x8 v = *(const bf16x8*)(Q + (size_t)(b * S_LEN + q0 + qr) * HID +
                                (kvh * 4 + head) * 64 + ch);
    bf16x8 w;
#pragma unroll
    for (int jj = 0; jj < 8; jj++) w[jj] = f2b(b2f(v[jj]) * 0.125f);
    *(bf16x8*)(lsQP + head * (32 * ST) + qr * ST + ch) = w;
  }
  __syncthreads();

  // hoist Q A-frags (loop-invariant). Safe vs lsP aliasing: every other
  // wave's first P-write is after the staging barrier below, which this
  // wave only enables after completing these reads.
  bf16x8 aq[2][2];
#pragma unroll
  for (int i = 0; i < 2; i++)
#pragma unroll
    for (int hh = 0; hh < 2; hh++)
      aq[i][hh] = *(const bf16x8*)(lsQP + wave * (32 * ST) +
                                   (i * 16 + lrow) * ST + hh * 32 + quad * 8);

  // per-lane softmax state: rows q = i*16 + quad*4 + r
  float m_st[2][4], l_st[2][4];
  f32x4 zero = {0.f, 0.f, 0.f, 0.f};
  f32x4 o[2][4];
#pragma unroll
  for (int i = 0; i < 2; i++)
#pragma unroll
    for (int r = 0; r < 4; r++) { m_st[i][r] = -1e30f; l_st[i][r] = 0.f; }
#pragma unroll
  for (int i = 0; i < 2; i++)
#pragma unroll
    for (int j = 0; j < 4; j++) o[i][j] = zero;

  const short* Kp = Kb + (size_t)b * S_LEN * KVD + kvh * 64;
  const short* Vp = Vb + (size_t)b * S_LEN * KVD + kvh * 64;

  // staging maps
  const int keyA = tid >> 3, chK = (tid & 7) * 8;     // K: 2 chunks/thread
  const int kpV = tid & 31, dcV = (tid >> 5) * 8;     // V: key-pair per thread

  // prefetch tile 0
  bf16x8 kf0 = *(const bf16x8*)(Kp + (size_t)keyA * KVD + chK);
  bf16x8 kf1 = *(const bf16x8*)(Kp + (size_t)(keyA + 32) * KVD + chK);
  bf16x8 vf0 = *(const bf16x8*)(Vp + (size_t)(2 * kpV) * KVD + dcV);
  bf16x8 vf1 = *(const bf16x8*)(Vp + (size_t)(2 * kpV + 1) * KVD + dcV);

  const int cW = 16 * (quad >> 1);          // P-store column XOR swizzle
  const int cR = 16 * ((lrow >> 3) & 1);    // matching P-read swizzle

  for (int k0 = 0; k0 < S_LEN; k0 += 64) {
    // ---- commit prefetched K tile + V^T tile to LDS ----
    *(bf16x8*)(lsK + keyA * ST + chK) = kf0;
    *(bf16x8*)(lsK + (keyA + 32) * ST + chK) = kf1;
#pragma unroll
    for (int jj = 0; jj < 8; jj++) {
      unsigned pk = (unsigned)(unsigned short)vf0[jj] |
                    ((unsigned)(unsigned short)vf1[jj] << 16);
      *(unsigned*)(lsVt + (dcV + jj) * ST + 2 * kpV) = pk;
    }
    __syncthreads();

    // ---- prefetch next tile (wraps on last iter; values unused) ----
    const int kn = (k0 + 64) & (S_LEN - 1);
    kf0 = *(const bf16x8*)(Kp + (size_t)(kn + keyA) * KVD + chK);
    kf1 = *(const bf16x8*)(Kp + (size_t)(kn + keyA + 32) * KVD + chK);
    vf0 = *(const bf16x8*)(Vp + (size_t)(kn + 2 * kpV) * KVD + dcV);
    vf1 = *(const bf16x8*)(Vp + (size_t)(kn + 2 * kpV + 1) * KVD + dcV);

    // ---- S = (Q/8) K^T : 32 q-rows x 64 keys per wave ----
    f32x4 s[2][4];
#pragma unroll
    for (int j = 0; j < 4; j++) {
      bf16x8 bk0 = *(const bf16x8*)(lsK + (j * 16 + lrow) * ST + quad * 8);
      bf16x8 bk1 = *(const bf16x8*)(lsK + (j * 16 + lrow) * ST + 32 + quad * 8);
#pragma unroll
      for (int i = 0; i < 2; i++) {
        f32x4 t = zero;
        t = __builtin_amdgcn_mfma_f32_16x16x32_bf16(aq[i][0], bk0, t, 0, 0, 0);
        t = __builtin_amdgcn_mfma_f32_16x16x32_bf16(aq[i][1], bk1, t, 0, 0, 0);
        s[i][j] = t;
      }
    }

    // ---- online softmax (row = over key: in-lane j + lrow butterfly) ----
#pragma unroll
    for (int i = 0; i < 2; i++)
#pragma unroll
      for (int r = 0; r < 4; r++) {
        float mx = fmaxf(fmaxf(s[i][0][r], s[i][1][r]),
                         fmaxf(s[i][2][r], s[i][3][r]));
#pragma unroll
        for (int off = 1; off < 16; off <<= 1) mx = fmaxf(mx, __shfl_xor(mx, off));
        const float mn = fmaxf(m_st[i][r], mx);
        const float alpha = __expf(m_st[i][r] - mn);
        m_st[i][r] = mn;
        float rs = 0.f;
#pragma unroll
        for (int j = 0; j < 4; j++) {
          const float p = __expf(s[i][j][r] - mn);
          rs += p;
          s[i][j][r] = p;                         // reuse s to hold P
        }
#pragma unroll
        for (int off = 1; off < 16; off <<= 1) rs += __shfl_xor(rs, off);
        l_st[i][r] = l_st[i][r] * alpha + rs;
#pragma unroll
        for (int jd = 0; jd < 4; jd++) o[i][jd][r] *= alpha;
      }

    // ---- P store (C-layout -> A-layout via per-wave LDS strip) ----
    short* Pw = lsQP + wave * (32 * ST);
#pragma unroll
    for (int i = 0; i < 2; i++)
#pragma unroll
      for (int j = 0; j < 4; j++)
#pragma unroll
        for (int r = 0; r < 4; r++)
          Pw[(i * 16 + quad * 4 + r) * ST + ((j * 16 + lrow) ^ cW)] = f2b(s[i][j][r]);

    // ---- O += P V ----
    bf16x8 ap[2][2];
#pragma unroll
    for (int i = 0; i < 2; i++)
#pragma unroll
      for (int hh = 0; hh < 2; hh++)
        ap[i][hh] = *(const bf16x8*)(Pw + (i * 16 + lrow) * ST +
                                     ((hh * 32 + quad * 8) ^ cR));
#pragma unroll
    for (int jd = 0; jd < 4; jd++) {
      bf16x8 bv0 = *(const bf16x8*)(lsVt + (jd * 16 + lrow) * ST + quad * 8);
      bf16x8 bv1 = *(const bf16x8*)(lsVt + (jd * 16 + lrow) * ST + 32 + quad * 8);
#pragma unroll
      for (int i = 0; i < 2; i++) {
        o[i][jd] = __builtin_amdgcn_mfma_f32_16x16x32_bf16(ap[i][0], bv0, o[i][jd], 0, 0, 0);
        o[i][jd] = __builtin_amdgcn_mfma_f32_16x16x32_bf16(ap[i][1], bv1, o[i][jd], 0, 0, 0);
      }
    }
    __syncthreads();   // protect lsK/lsVt before next commit
  }

  // ---- epilogue: normalize, store ----
#pragma unroll
  for (int i = 0; i < 2; i++)
#pragma unroll
    for (int jd = 0; jd < 4; jd++)
#pragma unroll
      for (int r = 0; r < 4; r++) {
        const int row = q0 + i * 16 + quad * 4 + r;
        const int col = h * 64 + jd * 16 + lrow;
        O[(size_t)(b * S_LEN + row) * HID + col] = f2b(o[i][jd][r] / l_st[i][r]);
      }
}

// ---------------------------------------------------------------------------
extern "C" void kernel_launch(void* const* d_in, const int* in_sizes, int n_in,
                              void* d_out, int out_size, void* d_ws, size_t ws_size,
                              hipStream_t stream) {
  const float* x  = (const float*)d_in[0];
  const float* wq = (const float*)d_in[1];
  const float* bq = (const float*)d_in[2];
  const float* wk = (const float*)d_in[3];
  const float* bk = (const float*)d_in[4];
  const float* wv = (const float*)d_in[5];
  const float* bv = (const float*)d_in[6];
  const float* wo = (const float*)d_in[7];
  const float* bo = (const float*)d_in[8];
  float* out = (float*)d_out;

  short* xb  = (short*)d_ws;
  short* wqb = xb  + (size_t)4096 * 2048;
  short* wkb = wqb + (size_t)2048 * 2048;
  short* wvb = wkb + (size_t)512 * 2048;
  short* wob = wvb + (size_t)512 * 2048;
  short* Qb  = wob + (size_t)2048 * 2048;
  short* Kb  = Qb  + (size_t)4096 * 2048;
  short* Vb  = Kb  + (size_t)4096 * 512;
  short* AO  = Vb  + (size_t)4096 * 512;

  dim3 blk(256);
  f32_to_bf16<<<4096 * 2048 / 1024, blk, 0, stream>>>(x,  xb,  4096 * 2048);
  f32_to_bf16<<<2048 * 2048 / 1024, blk, 0, stream>>>(wq, wqb, 2048 * 2048);
  f32_to_bf16<<< 512 * 2048 / 1024, blk, 0, stream>>>(wk, wkb, 512 * 2048);
  f32_to_bf16<<< 512 * 2048 / 1024, blk, 0, stream>>>(wv, wvb, 512 * 2048);
  f32_to_bf16<<<2048 * 2048 / 1024, blk, 0, stream>>>(wo, wob, 2048 * 2048);

  gemm_bt_bias<false><<<dim3(2048 / 128, 4096 / 128), blk, 0, stream>>>(xb, wqb, bq, Qb, 4096, 2048, 2048);
  gemm_bt_bias<false><<<dim3(512 / 128, 4096 / 128), blk, 0, stream>>>(xb, wkb, bk, Kb, 4096, 512, 2048);
  gemm_bt_bias<false><<<dim3(512 / 128, 4096 / 128), blk, 0, stream>>>(xb, wvb, bv, Vb, 4096, 512, 2048);
  gqa_flash<<<dim3(2048 / 32, 16), blk, 0, stream>>>(Qb, Kb, Vb, AO);
  gemm_bt_bias<true><<<dim3(2048 / 128, 4096 / 128), blk, 0, stream>>>(AO, wob, bo, out, 4096, 2048, 2048);
}

// Round 4
// 379.554 us; speedup vs baseline: 1.8908x; 1.4506x over previous
//
#include <hip/hip_runtime.h>

// ---------- types ----------
typedef __attribute__((ext_vector_type(8))) short bf16x8;   // 8 bf16 = 4 VGPR
typedef __attribute__((ext_vector_type(4))) float f32x4;    // MFMA C/D frag

__device__ __forceinline__ float b2f(short s) {
  union { unsigned u; float f; } c;
  c.u = ((unsigned)(unsigned short)s) << 16;
  return c.f;
}
__device__ __forceinline__ short f2b(float f) {
  union { unsigned u; float f; } c;
  c.f = f;
  unsigned r = (c.u + 0x7FFFu + ((c.u >> 16) & 1u)) >> 16;  // RNE
  return (short)r;
}
__device__ __forceinline__ short f2b_fast(float f) {        // round-half-up, 2 ops
  union { unsigned u; float f; } c;
  c.f = f;
  return (short)((c.u + 0x8000u) >> 16);
}

// async global->LDS, 16B per lane
__device__ __forceinline__ void async16(const void* g, void* l) {
  __builtin_amdgcn_global_load_lds(
      (const __attribute__((address_space(1))) unsigned*)g,
      (__attribute__((address_space(3))) unsigned*)l, 16, 0, 0);
}

// ---------------------------------------------------------------------------
// fp32 -> bf16 conversion pre-pass
// ---------------------------------------------------------------------------
__global__ __launch_bounds__(256)
void f32_to_bf16(const float* __restrict__ src, short* __restrict__ dst, int n) {
  int i = (blockIdx.x * blockDim.x + threadIdx.x) * 4;
  if (i < n) {
    float4 v = *(const float4*)(src + i);
    short4 o;
    o.x = f2b(v.x); o.y = f2b(v.y); o.z = f2b(v.z); o.w = f2b(v.w);
    *(short4*)(dst + i) = o;
  }
}

// ---------------------------------------------------------------------------
// Generic GEMM: C[M,N] = A @ Bw^T + bias (used for out-projection, fp32 out)
// ---------------------------------------------------------------------------
template <bool F32OUT>
__global__ __launch_bounds__(256)
void gemm_bt_bias(const short* __restrict__ A, const short* __restrict__ Bw,
                  const float* __restrict__ bias, void* __restrict__ Cv,
                  int M, int N, int K) {
  __shared__ short lsA[128 * 32];
  __shared__ short lsB[128 * 32];
  const int tid  = threadIdx.x;
  const int wave = tid >> 6, lane = tid & 63;
  const int quad = lane >> 4, lrow = lane & 15;
  const int m0 = blockIdx.y * 128, n0 = blockIdx.x * 128;
  const int wm = (wave >> 1) * 64, wn = (wave & 1) * 64;

  f32x4 zero = {0.f, 0.f, 0.f, 0.f};
  f32x4 acc[4][4];
#pragma unroll
  for (int i = 0; i < 4; i++)
#pragma unroll
    for (int j = 0; j < 4; j++) acc[i][j] = zero;

  const int r0 = tid >> 2, c0 = (tid & 3) * 8;
  const short* Ab  = A  + (size_t)(m0 + r0) * K + c0;
  const short* Ab2 = A  + (size_t)(m0 + r0 + 64) * K + c0;
  const short* Bb  = Bw + (size_t)(n0 + r0) * K + c0;
  const short* Bb2 = Bw + (size_t)(n0 + r0 + 64) * K + c0;

  for (int k0 = 0; k0 < K; k0 += 32) {
    async16(Ab  + k0, lsA + tid * 8);
    async16(Ab2 + k0, lsA + (tid + 256) * 8);
    async16(Bb  + k0, lsB + tid * 8);
    async16(Bb2 + k0, lsB + (tid + 256) * 8);
    __syncthreads();

    bf16x8 af[4], bfr[4];
#pragma unroll
    for (int i = 0; i < 4; i++)
      af[i] = *(const bf16x8*)(lsA + (wm + i * 16 + lrow) * 32 + quad * 8);
#pragma unroll
    for (int j = 0; j < 4; j++)
      bfr[j] = *(const bf16x8*)(lsB + (wn + j * 16 + lrow) * 32 + quad * 8);
#pragma unroll
    for (int i = 0; i < 4; i++)
#pragma unroll
      for (int j = 0; j < 4; j++)
        acc[i][j] = __builtin_amdgcn_mfma_f32_16x16x32_bf16(af[i], bfr[j], acc[i][j], 0, 0, 0);
    __syncthreads();
  }

#pragma unroll
  for (int j = 0; j < 4; j++) {
    const int col = n0 + wn + j * 16 + lrow;
    const float bv = bias[col];
#pragma unroll
    for (int i = 0; i < 4; i++) {
      const int rowb = m0 + wm + i * 16 + quad * 4;
#pragma unroll
      for (int r = 0; r < 4; r++) {
        const float val = acc[i][j][r] + bv;
        if (F32OUT)
          ((float*)Cv)[(size_t)(rowb + r) * N + col] = val;
        else
          ((short*)Cv)[(size_t)(rowb + r) * N + col] = f2b(val);
      }
    }
  }
}

// ---------------------------------------------------------------------------
// Fused QKV GEMM: Bw is the contiguous [3072][2048] concat of wq|wk|wv in ws.
// Epilogue scatters to Qo[4096x2048] / Ko[4096x512] / Vo[4096x512] by n0
// (block-uniform; 2048/2560 boundaries are 128-aligned).
// ---------------------------------------------------------------------------
__global__ __launch_bounds__(256)
void gemm_qkv(const short* __restrict__ A, const short* __restrict__ Bw,
              const float* __restrict__ bq, const float* __restrict__ bk,
              const float* __restrict__ bv,
              short* __restrict__ Qo, short* __restrict__ Ko, short* __restrict__ Vo) {
  const int K = 2048;
  __shared__ short lsA[128 * 32];
  __shared__ short lsB[128 * 32];
  const int tid  = threadIdx.x;
  const int wave = tid >> 6, lane = tid & 63;
  const int quad = lane >> 4, lrow = lane & 15;
  const int m0 = blockIdx.y * 128, n0 = blockIdx.x * 128;
  const int wm = (wave >> 1) * 64, wn = (wave & 1) * 64;

  f32x4 zero = {0.f, 0.f, 0.f, 0.f};
  f32x4 acc[4][4];
#pragma unroll
  for (int i = 0; i < 4; i++)
#pragma unroll
    for (int j = 0; j < 4; j++) acc[i][j] = zero;

  const int r0 = tid >> 2, c0 = (tid & 3) * 8;
  const short* Ab  = A  + (size_t)(m0 + r0) * K + c0;
  const short* Ab2 = A  + (size_t)(m0 + r0 + 64) * K + c0;
  const short* Bb  = Bw + (size_t)(n0 + r0) * K + c0;
  const short* Bb2 = Bw + (size_t)(n0 + r0 + 64) * K + c0;

  for (int k0 = 0; k0 < K; k0 += 32) {
    async16(Ab  + k0, lsA + tid * 8);
    async16(Ab2 + k0, lsA + (tid + 256) * 8);
    async16(Bb  + k0, lsB + tid * 8);
    async16(Bb2 + k0, lsB + (tid + 256) * 8);
    __syncthreads();

    bf16x8 af[4], bfr[4];
#pragma unroll
    for (int i = 0; i < 4; i++)
      af[i] = *(const bf16x8*)(lsA + (wm + i * 16 + lrow) * 32 + quad * 8);
#pragma unroll
    for (int j = 0; j < 4; j++)
      bfr[j] = *(const bf16x8*)(lsB + (wn + j * 16 + lrow) * 32 + quad * 8);
#pragma unroll
    for (int i = 0; i < 4; i++)
#pragma unroll
      for (int j = 0; j < 4; j++)
        acc[i][j] = __builtin_amdgcn_mfma_f32_16x16x32_bf16(af[i], bfr[j], acc[i][j], 0, 0, 0);
    __syncthreads();
  }

  // block-uniform scatter select
  short* base; int stride, coff; const float* bias;
  if (n0 < 2048)      { base = Qo; stride = 2048; bias = bq; coff = 0; }
  else if (n0 < 2560) { base = Ko; stride = 512;  bias = bk; coff = 2048; }
  else                { base = Vo; stride = 512;  bias = bv; coff = 2560; }

#pragma unroll
  for (int j = 0; j < 4; j++) {
    const int lc = n0 + wn + j * 16 + lrow - coff;
    const float bvv = bias[lc];
#pragma unroll
    for (int i = 0; i < 4; i++) {
      const int rowb = m0 + wm + i * 16 + quad * 4;
#pragma unroll
      for (int r = 0; r < 4; r++)
        base[(size_t)(rowb + r) * stride + lc] = f2b(acc[i][j][r] + bvv);
    }
  }
}

// ---------------------------------------------------------------------------
// Flash GQA v3: static-max softmax (p = exp(s) raw; |s| << 88 so no overflow;
// scale cancels in sum(p v)/sum(p)). Row-sums accumulated by MFMA against a
// constant ones-row (row 64) of the Vt tile -> accumulator column jd=4.
// Block = kv-head x 4 q-heads x 32 q-rows. LDS stride 72 (conflict-free).
// ---------------------------------------------------------------------------
#define S_LEN 2048
#define HID   2048
#define KVD   512
#define ST    72

__global__ __launch_bounds__(256)
void gqa_flash(const short* __restrict__ Q, const short* __restrict__ Kb,
               const short* __restrict__ Vb, short* __restrict__ O) {
  __shared__ __align__(16) short lsQP[4 * 32 * ST];   // Q strips, then P strips
  __shared__ __align__(16) short lsK[64 * ST];
  __shared__ __align__(16) short lsVt[80 * ST];       // rows 0-63: V^T; 64: ones; 65-79: 0

  const int tid  = threadIdx.x;
  const int wave = tid >> 6, lane = tid & 63;
  const int quad = lane >> 4, lrow = lane & 15;
  const int by = blockIdx.y, b = by >> 3, kvh = by & 7;
  const int h = kvh * 4 + wave;
  const int q0 = blockIdx.x * 32;

  // ---- stage Q once, scaled by 1/8 (exact in bf16) ----
  for (int c = tid; c < 1024; c += 256) {
    const int head = c >> 8, qr = (c >> 3) & 31, ch = (c & 7) * 8;
    bf16x8 v = *(const bf16x8*)(Q + (size_t)(b * S_LEN + q0 + qr) * HID +
                                (kvh * 4 + head) * 64 + ch);
    bf16x8 w;
#pragma unroll
    for (int jj = 0; jj < 8; jj++) w[jj] = f2b(b2f(v[jj]) * 0.125f);
    *(bf16x8*)(lsQP + head * (32 * ST) + qr * ST + ch) = w;
  }
  // ---- init constant Vt rows 64..79: row 64 = 1.0, rows 65-79 = 0 ----
  for (int c = tid; c < 16 * 36; c += 256) {
    const int rr = c / 36, dw = c - rr * 36;
    ((unsigned*)lsVt)[(64 + rr) * 36 + dw] = (rr == 0) ? 0x3F803F80u : 0u;
  }
  __syncthreads();

  // hoist Q A-frags (loop-invariant)
  bf16x8 aq[2][2];
#pragma unroll
  for (int i = 0; i < 2; i++)
#pragma unroll
    for (int hh = 0; hh < 2; hh++)
      aq[i][hh] = *(const bf16x8*)(lsQP + wave * (32 * ST) +
                                   (i * 16 + lrow) * ST + hh * 32 + quad * 8);
  // hoist ones-row B-frags (rows 64-79 never change)
  bf16x8 bv4a = *(const bf16x8*)(lsVt + (64 + lrow) * ST + quad * 8);
  bf16x8 bv4b = *(const bf16x8*)(lsVt + (64 + lrow) * ST + 32 + quad * 8);

  f32x4 zero = {0.f, 0.f, 0.f, 0.f};
  f32x4 o[2][5];                       // jd=4 column accumulates row-sums (l)
#pragma unroll
  for (int i = 0; i < 2; i++)
#pragma unroll
    for (int j = 0; j < 5; j++) o[i][j] = zero;

  const short* Kp = Kb + (size_t)b * S_LEN * KVD + kvh * 64;
  const short* Vp = Vb + (size_t)b * S_LEN * KVD + kvh * 64;

  const int keyA = tid >> 3, chK = (tid & 7) * 8;
  const int kpV = tid & 31, dcV = (tid >> 5) * 8;

  // prefetch tile 0
  bf16x8 kf0 = *(const bf16x8*)(Kp + (size_t)keyA * KVD + chK);
  bf16x8 kf1 = *(const bf16x8*)(Kp + (size_t)(keyA + 32) * KVD + chK);
  bf16x8 vf0 = *(const bf16x8*)(Vp + (size_t)(2 * kpV) * KVD + dcV);
  bf16x8 vf1 = *(const bf16x8*)(Vp + (size_t)(2 * kpV + 1) * KVD + dcV);

  const int cW = 16 * (quad >> 1);
  const int cR = 16 * ((lrow >> 3) & 1);
  short* Pw = lsQP + wave * (32 * ST);

  for (int k0 = 0; k0 < S_LEN; k0 += 64) {
    // ---- commit prefetched K + V^T to LDS ----
    *(bf16x8*)(lsK + keyA * ST + chK) = kf0;
    *(bf16x8*)(lsK + (keyA + 32) * ST + chK) = kf1;
#pragma unroll
    for (int jj = 0; jj < 8; jj++) {
      unsigned pk = (unsigned)(unsigned short)vf0[jj] |
                    ((unsigned)(unsigned short)vf1[jj] << 16);
      *(unsigned*)(lsVt + (dcV + jj) * ST + 2 * kpV) = pk;
    }
    __syncthreads();

    // ---- prefetch next tile ----
    const int kn = (k0 + 64) & (S_LEN - 1);
    kf0 = *(const bf16x8*)(Kp + (size_t)(kn + keyA) * KVD + chK);
    kf1 = *(const bf16x8*)(Kp + (size_t)(kn + keyA + 32) * KVD + chK);
    vf0 = *(const bf16x8*)(Vp + (size_t)(kn + 2 * kpV) * KVD + dcV);
    vf1 = *(const bf16x8*)(Vp + (size_t)(kn + 2 * kpV + 1) * KVD + dcV);

    // ---- S = (Q/8) K^T ----
    f32x4 s[2][4];
#pragma unroll
    for (int j = 0; j < 4; j++) {
      bf16x8 bk0 = *(const bf16x8*)(lsK + (j * 16 + lrow) * ST + quad * 8);
      bf16x8 bk1 = *(const bf16x8*)(lsK + (j * 16 + lrow) * ST + 32 + quad * 8);
#pragma unroll
      for (int i = 0; i < 2; i++) {
        f32x4 t = zero;
        t = __builtin_amdgcn_mfma_f32_16x16x32_bf16(aq[i][0], bk0, t, 0, 0, 0);
        t = __builtin_amdgcn_mfma_f32_16x16x32_bf16(aq[i][1], bk1, t, 0, 0, 0);
        s[i][j] = t;
      }
    }

    // ---- p = exp(s), store P strip (C-layout -> A-layout) ----
#pragma unroll
    for (int i = 0; i < 2; i++)
#pragma unroll
      for (int j = 0; j < 4; j++)
#pragma unroll
        for (int r = 0; r < 4; r++)
          Pw[(i * 16 + quad * 4 + r) * ST + ((j * 16 + lrow) ^ cW)] =
              f2b_fast(__expf(s[i][j][r]));

    // ---- O += P V ; column 64 (ones) accumulates l ----
    bf16x8 ap[2][2];
#pragma unroll
    for (int i = 0; i < 2; i++)
#pragma unroll
      for (int hh = 0; hh < 2; hh++)
        ap[i][hh] = *(const bf16x8*)(Pw + (i * 16 + lrow) * ST +
                                     ((hh * 32 + quad * 8) ^ cR));
#pragma unroll
    for (int jd = 0; jd < 4; jd++) {
      bf16x8 bv0 = *(const bf16x8*)(lsVt + (jd * 16 + lrow) * ST + quad * 8);
      bf16x8 bv1 = *(const bf16x8*)(lsVt + (jd * 16 + lrow) * ST + 32 + quad * 8);
#pragma unroll
      for (int i = 0; i < 2; i++) {
        o[i][jd] = __builtin_amdgcn_mfma_f32_16x16x32_bf16(ap[i][0], bv0, o[i][jd], 0, 0, 0);
        o[i][jd] = __builtin_amdgcn_mfma_f32_16x16x32_bf16(ap[i][1], bv1, o[i][jd], 0, 0, 0);
      }
    }
#pragma unroll
    for (int i = 0; i < 2; i++) {
      o[i][4] = __builtin_amdgcn_mfma_f32_16x16x32_bf16(ap[i][0], bv4a, o[i][4], 0, 0, 0);
      o[i][4] = __builtin_amdgcn_mfma_f32_16x16x32_bf16(ap[i][1], bv4b, o[i][4], 0, 0, 0);
    }
    __syncthreads();
  }

  // ---- epilogue: l lives in col 64 (lanes with lrow==0); broadcast, divide ----
#pragma unroll
  for (int i = 0; i < 2; i++)
#pragma unroll
    for (int r = 0; r < 4; r++) {
      const float l = __shfl(o[i][4][r], quad << 4);
      const float rl = 1.0f / l;
      const int row = q0 + i * 16 + quad * 4 + r;
#pragma unroll
      for (int jd = 0; jd < 4; jd++) {
        const int col = h * 64 + jd * 16 + lrow;
        O[(size_t)(b * S_LEN + row) * HID + col] = f2b(o[i][jd][r] * rl);
      }
    }
}

// ---------------------------------------------------------------------------
extern "C" void kernel_launch(void* const* d_in, const int* in_sizes, int n_in,
                              void* d_out, int out_size, void* d_ws, size_t ws_size,
                              hipStream_t stream) {
  const float* x  = (const float*)d_in[0];
  const float* wq = (const float*)d_in[1];
  const float* bq = (const float*)d_in[2];
  const float* wk = (const float*)d_in[3];
  const float* bk = (const float*)d_in[4];
  const float* wv = (const float*)d_in[5];
  const float* bv = (const float*)d_in[6];
  const float* wo = (const float*)d_in[7];
  const float* bo = (const float*)d_in[8];
  float* out = (float*)d_out;

  // wqb|wkb|wvb contiguous => single [3072][2048] QKV weight matrix
  short* xb  = (short*)d_ws;
  short* wqb = xb  + (size_t)4096 * 2048;
  short* wkb = wqb + (size_t)2048 * 2048;
  short* wvb = wkb + (size_t)512 * 2048;
  short* wob = wvb + (size_t)512 * 2048;
  short* Qb  = wob + (size_t)2048 * 2048;
  short* Kb  = Qb  + (size_t)4096 * 2048;
  short* Vb  = Kb  + (size_t)4096 * 512;
  short* AO  = Vb  + (size_t)4096 * 512;

  dim3 blk(256);
  f32_to_bf16<<<4096 * 2048 / 1024, blk, 0, stream>>>(x,  xb,  4096 * 2048);
  f32_to_bf16<<<2048 * 2048 / 1024, blk, 0, stream>>>(wq, wqb, 2048 * 2048);
  f32_to_bf16<<< 512 * 2048 / 1024, blk, 0, stream>>>(wk, wkb, 512 * 2048);
  f32_to_bf16<<< 512 * 2048 / 1024, blk, 0, stream>>>(wv, wvb, 512 * 2048);
  f32_to_bf16<<<2048 * 2048 / 1024, blk, 0, stream>>>(wo, wob, 2048 * 2048);

  gemm_qkv<<<dim3(3072 / 128, 4096 / 128), blk, 0, stream>>>(xb, wqb, bq, bk, bv, Qb, Kb, Vb);
  gqa_flash<<<dim3(2048 / 32, 16), blk, 0, stream>>>(Qb, Kb, Vb, AO);
  gemm_bt_bias<true><<<dim3(2048 / 128, 4096 / 128), blk, 0, stream>>>(AO, wob, bo, out, 4096, 2048, 2048);
}